// Round 17
// baseline (837.586 us; speedup 1.0000x reference)
//
#include <hip/hip_runtime.h>
#include <hip/hip_bf16.h>
#include <math.h>

// Problem constants
#define TT 64
#define BB 256      // per-sequence batch
#define BT 512      // total batch (both sequences)
#define DD 300      // embedding dim
#define HH 512      // hidden
#define G4 2048     // 4*H
#define KX 320      // padded x-region K
#define KW 512      // physical W-hi K
#define KC 64       // K chunk per LDS stage (gemm_x)
#define NCHX 5      // KX / KC

typedef __attribute__((ext_vector_type(8))) short short8v;
typedef __attribute__((ext_vector_type(4))) float f32x4;
typedef __attribute__((ext_vector_type(4))) unsigned short ushort4v;

#define MF(a, b, c) __builtin_amdgcn_mfma_f32_16x16x32_bf16(a, b, c, 0, 0, 0)

__device__ __forceinline__ unsigned short f2bf(float f) {
    union { float f; unsigned int u; } v; v.f = f;
    unsigned int u = v.u;
    u += 0x7fffu + ((u >> 16) & 1u);   // round-to-nearest-even
    return (unsigned short)(u >> 16);
}
__device__ __forceinline__ float bf2f(unsigned short s) {
    union { unsigned int u; float f; } v; v.u = ((unsigned int)s) << 16;
    return v.f;
}
__device__ __forceinline__ float sigm(float x) { return 1.0f / (1.0f + __expf(-x)); }
__device__ __forceinline__ float tanh_f(float x) {
    float ax = fabsf(x);
    if (ax > 15.0f) return (x > 0.0f) ? 1.0f : -1.0f;
    float e = __expf(2.0f * ax);
    float t = 1.0f - 2.0f / (e + 1.0f);
    return (x >= 0.0f) ? t : -t;
}

// ---------------------------------------------------------------------------
// Prep (R10-verified layouts):
//  WcatP[g'][KW]: g' = jt*64 + grp*16 + jj  <->  gate g = grp*512 + jt*16 + jj
//  WihP[g'][KX]: bf16 W_ih rows (zero-padded 300..319)
//  biasP[jt*64 + jj*4 + grp] = b_ih[g] + b_hh[g]
__global__ __launch_bounds__(256) void prep_w(const float* __restrict__ Wih,
                                              const float* __restrict__ Whh,
                                              const float* __restrict__ bih,
                                              const float* __restrict__ bhh,
                                              unsigned short* __restrict__ WcatP,
                                              unsigned short* __restrict__ WihP,
                                              float* __restrict__ biasP)
{
    const int gp = blockIdx.x;            // g' 0..2047
    const int jt = gp >> 6, r = gp & 63;
    const int grp = r >> 4, jj = r & 15;
    const int g = grp * 512 + jt * 16 + jj;

    for (int k = threadIdx.x; k < KW; k += 256)
        WcatP[(size_t)gp * KW + k] = f2bf(Whh[(size_t)g * HH + k]);
    for (int k = threadIdx.x; k < KX; k += 256)
        WihP[(size_t)gp * KX + k] = (k < DD) ? f2bf(Wih[(size_t)g * DD + k])
                                             : (unsigned short)0;
    if (threadIdx.x == 0) biasP[jt * 64 + jj * 4 + grp] = bih[g] + bhh[g];
}

// Prep: initial h (hi/lo bf16) and c.
__global__ __launch_bounds__(256) void prep_h(const float* __restrict__ h0a,
                                              const float* __restrict__ c0a,
                                              const float* __restrict__ h0b,
                                              const float* __restrict__ c0b,
                                              unsigned short* __restrict__ hhi,
                                              unsigned short* __restrict__ hlo,
                                              float* __restrict__ c)
{
    const int b = blockIdx.x; // 0..511
    for (int j = threadIdx.x; j < HH; j += 256) {
        float hv = (b < BB) ? h0a[b * HH + j] : h0b[(b - BB) * HH + j];
        float cv = (b < BB) ? c0a[b * HH + j] : c0b[(b - BB) * HH + j];
        unsigned short hi = f2bf(hv);
        hhi[b * HH + j] = hi;
        hlo[b * HH + j] = f2bf(hv - bf2f(hi));
        c[b * HH + j] = cv;
    }
}

// Pre-gather embeddings to bf16: Xbf[t*512+b][0..KX) (zero-padded past DD).
__global__ __launch_bounds__(256) void gather_x(const int* __restrict__ s1,
                                                const int* __restrict__ s2,
                                                const float* __restrict__ emb,
                                                unsigned short* __restrict__ Xbf)
{
    const int idx = blockIdx.x * 256 + threadIdx.x;   // TT*BT*40 threads
    const int row = idx / 40;          // t*512 + b
    const int seg = idx - row * 40;    // 8-elem segment within 320
    const int t = row >> 9;
    const int b = row & 511;
    const int tok = (b < BB) ? s1[t * BB + b] : s2[t * BB + (b - BB)];
    const int k = seg * 8;
    short8v v;
    if (k + 8 <= DD) {
        const float* e0 = emb + (size_t)tok * DD + k;
        float4 va = *(const float4*)e0;
        float4 vb = *(const float4*)(e0 + 4);
        v[0] = (short)f2bf(va.x); v[1] = (short)f2bf(va.y);
        v[2] = (short)f2bf(va.z); v[3] = (short)f2bf(va.w);
        v[4] = (short)f2bf(vb.x); v[5] = (short)f2bf(vb.y);
        v[6] = (short)f2bf(vb.z); v[7] = (short)f2bf(vb.w);
    } else {
        #pragma unroll
        for (int e = 0; e < 8; ++e) {
            int c = k + e;
            v[e] = (c < DD) ? (short)f2bf(emb[(size_t)tok * DD + c]) : (short)0;
        }
    }
    *(short8v*)&Xbf[(size_t)row * KX + k] = v;
}

// ---------------------------------------------------------------------------
// xprojP[m][g''] GEMM, 128x128 tile (R13/R15/R16-verified, byte-identical).
__global__ __launch_bounds__(512) void gemm_x(
    const unsigned short* __restrict__ Xbf,
    const unsigned short* __restrict__ WihP,
    unsigned short* __restrict__ xprojP)
{
    __shared__ __align__(16) unsigned short smem[16896];
    unsigned short* const As = smem;
    unsigned short* const Bs = smem + 8192;

    const int tid = threadIdx.x;
    const int xcd   = blockIdx.x & 7;
    const int local = blockIdx.x >> 3;        // 0..511
    const int mblk  = xcd * 32 + (local >> 4); // 0..255
    const int nblk  = local & 15;              // 0..15

    const int lane = tid & 63;
    const int wv  = tid >> 6;
    const int wr2 = wv >> 2;
    const int wc4 = wv & 3;
    const int r16 = lane & 15;
    const int kg8 = lane >> 4;

    const int srow = tid >> 2;
    const int q2   = (tid & 3) * 2;

    f32x4 acc[4][2] = {};

    auto load_chunk = [&](int ch, short8v* va, short8v* vb) {
        const int k0 = ch * KC;
        #pragma unroll
        for (int e = 0; e < 2; ++e) {
            va[e] = *(const short8v*)(Xbf + (size_t)(mblk * 128 + srow) * KX + k0 + (q2 + e) * 8);
            vb[e] = *(const short8v*)(WihP + (size_t)(nblk * 128 + srow) * KX + k0 + (q2 + e) * 8);
        }
    };
    auto write_chunk = [&](const short8v* va, const short8v* vb) {
        #pragma unroll
        for (int e = 0; e < 2; ++e) {
            const int g = ((q2 + e) ^ (srow & 7)) << 3;
            *(short8v*)&As[srow * 64 + g] = va[e];
            *(short8v*)&Bs[srow * 64 + g] = vb[e];
        }
    };
    auto lidx = [&](int r, int ko) { return r * 64 + ((((ko) >> 3) ^ (r & 7)) << 3); };

    short8v va[2], vb[2], na[2], nb[2];
    load_chunk(0, va, vb);
    for (int ch = 0; ch < NCHX; ++ch) {
        write_chunk(va, vb);
        if (ch + 1 < NCHX) load_chunk(ch + 1, na, nb);
        __syncthreads();
        #pragma unroll
        for (int ks = 0; ks < KC; ks += 32) {
            const int ko = ks + kg8 * 8;
            short8v a[4], b[2];
            #pragma unroll
            for (int i = 0; i < 4; ++i)
                a[i] = *(const short8v*)&As[lidx(64 * wr2 + 16 * i + r16, ko)];
            #pragma unroll
            for (int j = 0; j < 2; ++j)
                b[j] = *(const short8v*)&Bs[lidx(32 * wc4 + 16 * j + r16, ko)];
            #pragma unroll
            for (int i = 0; i < 4; ++i)
                #pragma unroll
                for (int j = 0; j < 2; ++j)
                    acc[i][j] = __builtin_amdgcn_mfma_f32_16x16x32_bf16(a[i], b[j], acc[i][j], 0, 0, 0);
        }
        __syncthreads();
        #pragma unroll
        for (int e = 0; e < 2; ++e) { va[e] = na[e]; vb[e] = nb[e]; }
    }

    float* gbuf = (float*)smem;          // 64 x 132 floats
    const int jj5 = tid & 31;
    const int hh  = jj5 >> 4;
    const int jj  = jj5 & 15;
    const int row0 = tid >> 5;
    #pragma unroll
    for (int p = 0; p < 2; ++p) {
        if (p) __syncthreads();
        if (wr2 == p) {
            #pragma unroll
            for (int i = 0; i < 4; ++i)
                #pragma unroll
                for (int j = 0; j < 2; ++j)
                    #pragma unroll
                    for (int r = 0; r < 4; ++r)
                        gbuf[(16 * i + 4 * kg8 + r) * 132 + 32 * wc4 + 16 * j + r16]
                            = acc[i][j][r];
        }
        __syncthreads();
        #pragma unroll
        for (int u = 0; u < 4; ++u) {
            const int row = row0 + 16 * u;
            const size_t m = (size_t)(mblk * 128 + p * 64 + row);
            ushort4v o;
            #pragma unroll
            for (int grp = 0; grp < 4; ++grp)
                o[grp] = f2bf(gbuf[row * 132 + hh * 64 + grp * 16 + jj]);
            __builtin_nontemporal_store(o,
                (ushort4v*)&xprojP[m * G4 + (nblk * 2 + hh) * 64 + jj * 4]);
        }
    }
}

// ---------------------------------------------------------------------------
// One LSTM timestep. B panel (64 gate-rows x K=512 = 64 KB) staged ONCE into
// LDS (verified XOR-swizzle); barrier-free K-loop with per-lane direct global
// A loads (contiguous 16B, XCD-local L2). MFMA slice set and accumulation
// order bit-identical to R16.
__global__ __launch_bounds__(256, 2) void lstm_step(
    const unsigned short* __restrict__ WcatP,
    const float* __restrict__ biasP,
    const unsigned short* __restrict__ xprojP,
    const unsigned short* __restrict__ hhi_in,
    const unsigned short* __restrict__ hlo_in,
    float* __restrict__ cbuf,
    unsigned short* __restrict__ hhi_out,
    unsigned short* __restrict__ hlo_out,
    int t)
{
    __shared__ __align__(16) unsigned short Bsm[64 * 512];  // 64 KB; gbuf aliases

    const int tid = threadIdx.x;
    const int bid = blockIdx.x;

    // XCD-aware decode: each XCD owns 4 contiguous jt tiles.
    const int xcd   = bid & 7;
    const int local = bid >> 3;
    const int bx    = local & 7;
    const int jt    = xcd * 4 + (local >> 3);

    const int lane = tid & 63;
    const int w = tid >> 6;
    const int wr = w >> 1, wc = w & 1;
    const int r16 = lane & 15;
    const int kg8 = lane >> 4;

    // ---- stage full B panel, swizzled (q -> q^(row&7), per-octet) ----
    {
        const int r  = tid >> 2;          // 0..63
        const int q0 = (tid & 3) * 16;    // octet base (64 octets per row)
        const unsigned short* bsrc = WcatP + (size_t)(jt * 64 + r) * KW;
        #pragma unroll
        for (int i = 0; i < 16; ++i) {
            const int q  = q0 + i;
            const int qs = q ^ (r & 7);
            *(short8v*)&Bsm[r * 512 + qs * 8] = *(const short8v*)(bsrc + q * 8);
        }
    }

    // epilogue prefetch (independent of h)
    const int jj = tid & 15;
    const int row0 = tid >> 4;
    const f32x4 bp = *(const f32x4*)&biasP[jt * 64 + jj * 4];
    ushort4v xp[4]; float cp[4];
    #pragma unroll
    for (int u = 0; u < 4; ++u) {
        int batch = bx * 64 + row0 + 16 * u;
        xp[u] = __builtin_nontemporal_load(
            (const ushort4v*)&xprojP[((size_t)t * BT + batch) * G4 + jt * 64 + jj * 4]);
        cp[u] = cbuf[batch * HH + jt * 16 + jj];
    }

    __syncthreads();   // B panel visible

    // ---- barrier-free K loop: A direct from global, B from resident LDS ----
    const unsigned short* arow0 = hhi_in + (size_t)(bx * 64 + 32 * wr + r16) * HH;
    const unsigned short* arow1 = arow0 + (size_t)16 * HH;
    const int br0 = (32 * wc + r16) * 512;
    const int br1 = br0 + 16 * 512;

    f32x4 acc[2][2] = {};
    #pragma unroll
    for (int ks = 0; ks < 16; ++ks) {
        const int ko = ks * 32 + kg8 * 8;                       // global k offset
        const int qs = ((ks * 4 + kg8) ^ (r16 & 7)) * 8;        // swizzled octet
        short8v a0 = *(const short8v*)(arow0 + ko);
        short8v a1 = *(const short8v*)(arow1 + ko);
        short8v b0 = *(const short8v*)&Bsm[br0 + qs];
        short8v b1 = *(const short8v*)&Bsm[br1 + qs];
        acc[0][0] = MF(a0, b0, acc[0][0]);
        acc[0][1] = MF(a0, b1, acc[0][1]);
        acc[1][0] = MF(a1, b0, acc[1][0]);
        acc[1][1] = MF(a1, b1, acc[1][1]);
    }

    __syncthreads();   // all B reads done; alias LDS as gbuf

    // gate exchange (verified C/D mapping: row=(lane>>4)*4+reg, col=lane&15)
    float* gbuf = (float*)Bsm;   // 64 x 65 floats = 16.6 KB < 64 KB
    #pragma unroll
    for (int i = 0; i < 2; ++i)
        #pragma unroll
        for (int j2 = 0; j2 < 2; ++j2)
            #pragma unroll
            for (int r = 0; r < 4; ++r) {
                int grow = (2 * wr + i) * 16 + kg8 * 4 + r;
                int gcol = (2 * wc + j2) * 16 + r16;
                gbuf[grow * 65 + gcol] = acc[i][j2][r];
            }
    __syncthreads();

    #pragma unroll
    for (int u = 0; u < 4; ++u) {
        int row = row0 + 16 * u;
        int batch = bx * 64 + row;
        int j = jt * 16 + jj;
        float gi = gbuf[row * 65 +      jj] + bp[0] + bf2f(xp[u][0]);
        float gf = gbuf[row * 65 + 16 + jj] + bp[1] + bf2f(xp[u][1]);
        float gg = gbuf[row * 65 + 32 + jj] + bp[2] + bf2f(xp[u][2]);
        float go = gbuf[row * 65 + 48 + jj] + bp[3] + bf2f(xp[u][3]);
        float cn = sigm(gf) * cp[u] + sigm(gi) * tanh_f(gg);
        float hn = sigm(go) * tanh_f(cn);
        cbuf[batch * HH + j] = cn;
        unsigned short hi = f2bf(hn);
        hhi_out[batch * HH + j] = hi;
        hlo_out[batch * HH + j] = f2bf(hn - bf2f(hi));  // kept for finalize precision
    }
}

// ---------------------------------------------------------------------------
__global__ __launch_bounds__(64) void finalize(const unsigned short* __restrict__ hhi,
                                               const unsigned short* __restrict__ hlo,
                                               float* __restrict__ out)
{
    const int b = blockIdx.x;       // 0..255
    const int lane = threadIdx.x;   // 64
    float s = 0.0f;
    for (int j = lane; j < HH; j += 64) {
        float ha = bf2f(hhi[b * HH + j]) + bf2f(hlo[b * HH + j]);
        float hb = bf2f(hhi[(b + BB) * HH + j]) + bf2f(hlo[(b + BB) * HH + j]);
        s += fabsf(ha - hb);
    }
    #pragma unroll
    for (int off = 32; off > 0; off >>= 1) s += __shfl_down(s, off);
    if (lane == 0) out[b] = expf(-s);
}

// ---------------------------------------------------------------------------
extern "C" void kernel_launch(void* const* d_in, const int* in_sizes, int n_in,
                              void* d_out, int out_size, void* d_ws, size_t ws_size,
                              hipStream_t stream)
{
    const int*   s1  = (const int*)d_in[0];
    const int*   s2  = (const int*)d_in[1];
    const float* emb = (const float*)d_in[2];
    const float* Wih = (const float*)d_in[3];
    const float* Whh = (const float*)d_in[4];
    const float* bih = (const float*)d_in[5];
    const float* bhh = (const float*)d_in[6];
    const float* h0a = (const float*)d_in[7];
    const float* c0a = (const float*)d_in[8];
    const float* h0b = (const float*)d_in[9];
    const float* c0b = (const float*)d_in[10];
    float* out = (float*)d_out;

    char* ws = (char*)d_ws;
    size_t off = 0;
    unsigned short* WcatP = (unsigned short*)(ws + off); off += (size_t)G4 * KW * 2;   // 2 MB
    unsigned short* WihP  = (unsigned short*)(ws + off); off += (size_t)G4 * KX * 2;   // 1.3 MB
    float* biasP          = (float*)(ws + off);          off += (size_t)G4 * 4;
    unsigned short* hhi0  = (unsigned short*)(ws + off); off += (size_t)BT * HH * 2;
    unsigned short* hhi1  = (unsigned short*)(ws + off); off += (size_t)BT * HH * 2;
    unsigned short* hlo0  = (unsigned short*)(ws + off); off += (size_t)BT * HH * 2;
    unsigned short* hlo1  = (unsigned short*)(ws + off); off += (size_t)BT * HH * 2;
    float* cbuf           = (float*)(ws + off);          off += (size_t)BT * HH * 4;   // 1 MB
    unsigned short* Xbf   = (unsigned short*)(ws + off); off += (size_t)TT * BT * KX * 2; // 21 MB
    unsigned short* xprojP= (unsigned short*)(ws + off); off += (size_t)TT * BT * G4 * 2; // 134 MB

    prep_w<<<G4, 256, 0, stream>>>(Wih, Whh, bih, bhh, WcatP, WihP, biasP);
    prep_h<<<BT, 256, 0, stream>>>(h0a, c0a, h0b, c0b, hhi0, hlo0, cbuf);
    gather_x<<<(TT * BT * 40) / 256, 256, 0, stream>>>(s1, s2, emb, Xbf);
    gemm_x<<<4096, 512, 0, stream>>>(Xbf, WihP, xprojP);

    unsigned short* hhi[2] = { hhi0, hhi1 };
    unsigned short* hlo[2] = { hlo0, hlo1 };
    for (int t = 0; t < TT; ++t) {
        int pi = t & 1, po = pi ^ 1;
        lstm_step<<<256, 256, 0, stream>>>(WcatP, biasP, xprojP,
                                           hhi[pi], hlo[pi], cbuf,
                                           hhi[po], hlo[po], t);
    }
    // t=63 (odd) writes buffer 0
    finalize<<<BB, 64, 0, stream>>>(hhi0, hlo0, out);
}

// Round 18
// 463.434 us; speedup vs baseline: 1.8073x; 1.8073x over previous
//
#include <hip/hip_runtime.h>
#include <hip/hip_bf16.h>
#include <math.h>

// Problem constants
#define TT 64
#define BB 256      // per-sequence batch
#define BT 512      // total batch (both sequences)
#define DD 300      // embedding dim
#define HH 512      // hidden
#define G4 2048     // 4*H
#define KX 320      // padded x-region K
#define KW 512      // physical W-hi K
#define KC 64       // K chunk per LDS stage
#define NCHX 5      // KX / KC
#define NCHH 8      // 512 / KC (1-term recurrent matmul: h_hi * W_hi)

typedef __attribute__((ext_vector_type(8))) short short8v;
typedef __attribute__((ext_vector_type(4))) float f32x4;
typedef __attribute__((ext_vector_type(4))) unsigned short ushort4v;

__device__ __forceinline__ unsigned short f2bf(float f) {
    union { float f; unsigned int u; } v; v.f = f;
    unsigned int u = v.u;
    u += 0x7fffu + ((u >> 16) & 1u);   // round-to-nearest-even
    return (unsigned short)(u >> 16);
}
__device__ __forceinline__ float bf2f(unsigned short s) {
    union { unsigned int u; float f; } v; v.u = ((unsigned int)s) << 16;
    return v.f;
}
__device__ __forceinline__ float sigm(float x) { return 1.0f / (1.0f + __expf(-x)); }
__device__ __forceinline__ float tanh_f(float x) {
    float ax = fabsf(x);
    if (ax > 15.0f) return (x > 0.0f) ? 1.0f : -1.0f;
    float e = __expf(2.0f * ax);
    float t = 1.0f - 2.0f / (e + 1.0f);
    return (x >= 0.0f) ? t : -t;
}

// ---------------------------------------------------------------------------
// Prep (R10-verified layouts):
//  WcatP[g'][KW]: g' = jt*64 + grp*16 + jj  <->  gate g = grp*512 + jt*16 + jj
//  WihP[g'][KX]: bf16 W_ih rows (zero-padded 300..319)
//  biasP[jt*64 + jj*4 + grp] = b_ih[g] + b_hh[g]
__global__ __launch_bounds__(256) void prep_w(const float* __restrict__ Wih,
                                              const float* __restrict__ Whh,
                                              const float* __restrict__ bih,
                                              const float* __restrict__ bhh,
                                              unsigned short* __restrict__ WcatP,
                                              unsigned short* __restrict__ WihP,
                                              float* __restrict__ biasP)
{
    const int gp = blockIdx.x;            // g' 0..2047
    const int jt = gp >> 6, r = gp & 63;
    const int grp = r >> 4, jj = r & 15;
    const int g = grp * 512 + jt * 16 + jj;

    for (int k = threadIdx.x; k < KW; k += 256)
        WcatP[(size_t)gp * KW + k] = f2bf(Whh[(size_t)g * HH + k]);
    for (int k = threadIdx.x; k < KX; k += 256)
        WihP[(size_t)gp * KX + k] = (k < DD) ? f2bf(Wih[(size_t)g * DD + k])
                                             : (unsigned short)0;
    if (threadIdx.x == 0) biasP[jt * 64 + jj * 4 + grp] = bih[g] + bhh[g];
}

// Prep: initial h (hi/lo bf16) and c.
__global__ __launch_bounds__(256) void prep_h(const float* __restrict__ h0a,
                                              const float* __restrict__ c0a,
                                              const float* __restrict__ h0b,
                                              const float* __restrict__ c0b,
                                              unsigned short* __restrict__ hhi,
                                              unsigned short* __restrict__ hlo,
                                              float* __restrict__ c)
{
    const int b = blockIdx.x; // 0..511
    for (int j = threadIdx.x; j < HH; j += 256) {
        float hv = (b < BB) ? h0a[b * HH + j] : h0b[(b - BB) * HH + j];
        float cv = (b < BB) ? c0a[b * HH + j] : c0b[(b - BB) * HH + j];
        unsigned short hi = f2bf(hv);
        hhi[b * HH + j] = hi;
        hlo[b * HH + j] = f2bf(hv - bf2f(hi));
        c[b * HH + j] = cv;
    }
}

// Pre-gather embeddings to bf16: Xbf[t*512+b][0..KX) (zero-padded past DD).
__global__ __launch_bounds__(256) void gather_x(const int* __restrict__ s1,
                                                const int* __restrict__ s2,
                                                const float* __restrict__ emb,
                                                unsigned short* __restrict__ Xbf)
{
    const int idx = blockIdx.x * 256 + threadIdx.x;   // TT*BT*40 threads
    const int row = idx / 40;          // t*512 + b
    const int seg = idx - row * 40;    // 8-elem segment within 320
    const int t = row >> 9;
    const int b = row & 511;
    const int tok = (b < BB) ? s1[t * BB + b] : s2[t * BB + (b - BB)];
    const int k = seg * 8;
    short8v v;
    if (k + 8 <= DD) {
        const float* e0 = emb + (size_t)tok * DD + k;
        float4 va = *(const float4*)e0;
        float4 vb = *(const float4*)(e0 + 4);
        v[0] = (short)f2bf(va.x); v[1] = (short)f2bf(va.y);
        v[2] = (short)f2bf(va.z); v[3] = (short)f2bf(va.w);
        v[4] = (short)f2bf(vb.x); v[5] = (short)f2bf(vb.y);
        v[6] = (short)f2bf(vb.z); v[7] = (short)f2bf(vb.w);
    } else {
        #pragma unroll
        for (int e = 0; e < 8; ++e) {
            int c = k + e;
            v[e] = (c < DD) ? (short)f2bf(emb[(size_t)tok * DD + c]) : (short)0;
        }
    }
    *(short8v*)&Xbf[(size_t)row * KX + k] = v;
}

// ---------------------------------------------------------------------------
// xprojP[m][g''] GEMM, 128x128 tile (R13/R15/R16-verified, byte-identical).
__global__ __launch_bounds__(512) void gemm_x(
    const unsigned short* __restrict__ Xbf,
    const unsigned short* __restrict__ WihP,
    unsigned short* __restrict__ xprojP)
{
    __shared__ __align__(16) unsigned short smem[16896];
    unsigned short* const As = smem;
    unsigned short* const Bs = smem + 8192;

    const int tid = threadIdx.x;
    const int xcd   = blockIdx.x & 7;
    const int local = blockIdx.x >> 3;        // 0..511
    const int mblk  = xcd * 32 + (local >> 4); // 0..255
    const int nblk  = local & 15;              // 0..15

    const int lane = tid & 63;
    const int wv  = tid >> 6;
    const int wr2 = wv >> 2;
    const int wc4 = wv & 3;
    const int r16 = lane & 15;
    const int kg8 = lane >> 4;

    const int srow = tid >> 2;
    const int q2   = (tid & 3) * 2;

    f32x4 acc[4][2] = {};

    auto load_chunk = [&](int ch, short8v* va, short8v* vb) {
        const int k0 = ch * KC;
        #pragma unroll
        for (int e = 0; e < 2; ++e) {
            va[e] = *(const short8v*)(Xbf + (size_t)(mblk * 128 + srow) * KX + k0 + (q2 + e) * 8);
            vb[e] = *(const short8v*)(WihP + (size_t)(nblk * 128 + srow) * KX + k0 + (q2 + e) * 8);
        }
    };
    auto write_chunk = [&](const short8v* va, const short8v* vb) {
        #pragma unroll
        for (int e = 0; e < 2; ++e) {
            const int g = ((q2 + e) ^ (srow & 7)) << 3;
            *(short8v*)&As[srow * 64 + g] = va[e];
            *(short8v*)&Bs[srow * 64 + g] = vb[e];
        }
    };
    auto lidx = [&](int r, int ko) { return r * 64 + ((((ko) >> 3) ^ (r & 7)) << 3); };

    short8v va[2], vb[2], na[2], nb[2];
    load_chunk(0, va, vb);
    for (int ch = 0; ch < NCHX; ++ch) {
        write_chunk(va, vb);
        if (ch + 1 < NCHX) load_chunk(ch + 1, na, nb);
        __syncthreads();
        #pragma unroll
        for (int ks = 0; ks < KC; ks += 32) {
            const int ko = ks + kg8 * 8;
            short8v a[4], b[2];
            #pragma unroll
            for (int i = 0; i < 4; ++i)
                a[i] = *(const short8v*)&As[lidx(64 * wr2 + 16 * i + r16, ko)];
            #pragma unroll
            for (int j = 0; j < 2; ++j)
                b[j] = *(const short8v*)&Bs[lidx(32 * wc4 + 16 * j + r16, ko)];
            #pragma unroll
            for (int i = 0; i < 4; ++i)
                #pragma unroll
                for (int j = 0; j < 2; ++j)
                    acc[i][j] = __builtin_amdgcn_mfma_f32_16x16x32_bf16(a[i], b[j], acc[i][j], 0, 0, 0);
        }
        __syncthreads();
        #pragma unroll
        for (int e = 0; e < 2; ++e) { va[e] = na[e]; vb[e] = nb[e]; }
    }

    float* gbuf = (float*)smem;          // 64 x 132 floats
    const int jj5 = tid & 31;
    const int hh  = jj5 >> 4;
    const int jj  = jj5 & 15;
    const int row0 = tid >> 5;
    #pragma unroll
    for (int p = 0; p < 2; ++p) {
        if (p) __syncthreads();
        if (wr2 == p) {
            #pragma unroll
            for (int i = 0; i < 4; ++i)
                #pragma unroll
                for (int j = 0; j < 2; ++j)
                    #pragma unroll
                    for (int r = 0; r < 4; ++r)
                        gbuf[(16 * i + 4 * kg8 + r) * 132 + 32 * wc4 + 16 * j + r16]
                            = acc[i][j][r];
        }
        __syncthreads();
        #pragma unroll
        for (int u = 0; u < 4; ++u) {
            const int row = row0 + 16 * u;
            const size_t m = (size_t)(mblk * 128 + p * 64 + row);
            ushort4v o;
            #pragma unroll
            for (int grp = 0; grp < 4; ++grp)
                o[grp] = f2bf(gbuf[row * 132 + hh * 64 + grp * 16 + jj]);
            __builtin_nontemporal_store(o,
                (ushort4v*)&xprojP[m * G4 + (nblk * 2 + hh) * 64 + jj * 4]);
        }
    }
}

// ---------------------------------------------------------------------------
// One LSTM timestep (R16-verified, byte-identical). 1-term recurrent matmul:
// A = h_hi only (K=512, 8 chunks). h_lo still STORED each step so the
// final-step readout (finalize) keeps hi+lo precision. Same dbuf/swizzle.
__global__ __launch_bounds__(256) void lstm_step(
    const unsigned short* __restrict__ WcatP,
    const float* __restrict__ biasP,
    const unsigned short* __restrict__ xprojP,
    const unsigned short* __restrict__ hhi_in,
    const unsigned short* __restrict__ hlo_in,
    float* __restrict__ cbuf,
    unsigned short* __restrict__ hhi_out,
    unsigned short* __restrict__ hlo_out,
    int t)
{
    __shared__ __align__(16) unsigned short As0[64 * 64], As1[64 * 64];
    __shared__ __align__(16) unsigned short Bs0[64 * 64], Bs1[64 * 64];
    __shared__ __align__(16) float gbuf[64 * 65];

    const int tid = threadIdx.x;
    const int bid = blockIdx.x;

    // XCD-aware decode: each XCD owns 4 contiguous jt tiles.
    const int xcd   = bid & 7;
    const int local = bid >> 3;
    const int bx    = local & 7;
    const int jt    = xcd * 4 + (local >> 3);

    const int lane = tid & 63;
    const int w = tid >> 6;
    const int wr = w >> 1, wc = w & 1;
    const int r16 = lane & 15;
    const int kg8 = lane >> 4;
    const int sl8 = lane >> 3;
    const int gd  = lane & 7;

    f32x4 acc[2][2] = {};

    auto load_chunk = [&](int ch, short8v* va, short8v* vb) {
        const int k0 = ch * KC;
        const unsigned short* abase = hhi_in + (size_t)(bx * 64) * HH + k0;
        #pragma unroll
        for (int s = 0; s < 2; ++s) {
            const int r = w * 16 + s * 8 + sl8;
            va[s] = *(const short8v*)(abase + (size_t)r * HH + gd * 8);
            vb[s] = *(const short8v*)(WcatP + (size_t)(jt * 64 + r) * KW + k0 + gd * 8);
        }
    };
    auto write_chunk = [&](unsigned short* A, unsigned short* B,
                           const short8v* va, const short8v* vb) {
        #pragma unroll
        for (int s = 0; s < 2; ++s) {
            const int r = w * 16 + s * 8 + sl8;
            const int g = (gd ^ sl8) << 3;     // r&7 == sl8
            *(short8v*)&A[r * 64 + g] = va[s];
            *(short8v*)&B[r * 64 + g] = vb[s];
        }
    };
    auto lidx = [&](int r, int ko) { return r * 64 + ((((ko) >> 3) ^ (r & 7)) << 3); };
    auto compute = [&](const unsigned short* A, const unsigned short* B) {
        #pragma unroll
        for (int ks = 0; ks < KC; ks += 32) {
            const int ko = ks + kg8 * 8;
            short8v a0 = *(const short8v*)&A[lidx(32 * wr + r16,      ko)];
            short8v a1 = *(const short8v*)&A[lidx(32 * wr + 16 + r16, ko)];
            short8v b0 = *(const short8v*)&B[lidx(32 * wc + r16,      ko)];
            short8v b1 = *(const short8v*)&B[lidx(32 * wc + 16 + r16, ko)];
            acc[0][0] = __builtin_amdgcn_mfma_f32_16x16x32_bf16(a0, b0, acc[0][0], 0, 0, 0);
            acc[0][1] = __builtin_amdgcn_mfma_f32_16x16x32_bf16(a0, b1, acc[0][1], 0, 0, 0);
            acc[1][0] = __builtin_amdgcn_mfma_f32_16x16x32_bf16(a1, b0, acc[1][0], 0, 0, 0);
            acc[1][1] = __builtin_amdgcn_mfma_f32_16x16x32_bf16(a1, b1, acc[1][1], 0, 0, 0);
        }
    };

    short8v ra[2], rb[2], sa[2], sb[2];
    load_chunk(0, ra, rb);
    load_chunk(1, sa, sb);

    // epilogue prefetch
    const int jj = tid & 15;
    const int row0 = tid >> 4;
    const f32x4 bp = *(const f32x4*)&biasP[jt * 64 + jj * 4];
    ushort4v xp[4]; float cp[4];
    #pragma unroll
    for (int u = 0; u < 4; ++u) {
        int batch = bx * 64 + row0 + 16 * u;
        xp[u] = __builtin_nontemporal_load(
            (const ushort4v*)&xprojP[((size_t)t * BT + batch) * G4 + jt * 64 + jj * 4]);
        cp[u] = cbuf[batch * HH + jt * 16 + jj];
    }

    write_chunk(As0, Bs0, ra, rb);
    __syncthreads();

    for (int ch = 0; ch < NCHH; ch += 2) {
        if (ch + 2 < NCHH) load_chunk(ch + 2, ra, rb);
        write_chunk(As1, Bs1, sa, sb);       // chunk ch+1 (NCHH even)
        compute(As0, Bs0);                    // chunk ch
        __syncthreads();
        if (ch + 3 < NCHH) load_chunk(ch + 3, sa, sb);
        if (ch + 2 < NCHH) write_chunk(As0, Bs0, ra, rb);
        compute(As1, Bs1);                    // chunk ch+1
        __syncthreads();
    }

    // gate exchange (verified C/D mapping: row=(lane>>4)*4+reg, col=lane&15)
    #pragma unroll
    for (int i = 0; i < 2; ++i)
        #pragma unroll
        for (int j2 = 0; j2 < 2; ++j2)
            #pragma unroll
            for (int r = 0; r < 4; ++r) {
                int grow = (2 * wr + i) * 16 + kg8 * 4 + r;
                int gcol = (2 * wc + j2) * 16 + r16;
                gbuf[grow * 65 + gcol] = acc[i][j2][r];
            }
    __syncthreads();

    #pragma unroll
    for (int u = 0; u < 4; ++u) {
        int row = row0 + 16 * u;
        int batch = bx * 64 + row;
        int j = jt * 16 + jj;
        float gi = gbuf[row * 65 +      jj] + bp[0] + bf2f(xp[u][0]);
        float gf = gbuf[row * 65 + 16 + jj] + bp[1] + bf2f(xp[u][1]);
        float gg = gbuf[row * 65 + 32 + jj] + bp[2] + bf2f(xp[u][2]);
        float go = gbuf[row * 65 + 48 + jj] + bp[3] + bf2f(xp[u][3]);
        float cn = sigm(gf) * cp[u] + sigm(gi) * tanh_f(gg);
        float hn = sigm(go) * tanh_f(cn);
        cbuf[batch * HH + j] = cn;
        unsigned short hi = f2bf(hn);
        hhi_out[batch * HH + j] = hi;
        hlo_out[batch * HH + j] = f2bf(hn - bf2f(hi));  // kept for finalize precision
    }
}

// ---------------------------------------------------------------------------
__global__ __launch_bounds__(64) void finalize(const unsigned short* __restrict__ hhi,
                                               const unsigned short* __restrict__ hlo,
                                               float* __restrict__ out)
{
    const int b = blockIdx.x;       // 0..255
    const int lane = threadIdx.x;   // 64
    float s = 0.0f;
    for (int j = lane; j < HH; j += 64) {
        float ha = bf2f(hhi[b * HH + j]) + bf2f(hlo[b * HH + j]);
        float hb = bf2f(hhi[(b + BB) * HH + j]) + bf2f(hlo[(b + BB) * HH + j]);
        s += fabsf(ha - hb);
    }
    #pragma unroll
    for (int off = 32; off > 0; off >>= 1) s += __shfl_down(s, off);
    if (lane == 0) out[b] = expf(-s);
}

// ---------------------------------------------------------------------------
extern "C" void kernel_launch(void* const* d_in, const int* in_sizes, int n_in,
                              void* d_out, int out_size, void* d_ws, size_t ws_size,
                              hipStream_t stream)
{
    const int*   s1  = (const int*)d_in[0];
    const int*   s2  = (const int*)d_in[1];
    const float* emb = (const float*)d_in[2];
    const float* Wih = (const float*)d_in[3];
    const float* Whh = (const float*)d_in[4];
    const float* bih = (const float*)d_in[5];
    const float* bhh = (const float*)d_in[6];
    const float* h0a = (const float*)d_in[7];
    const float* c0a = (const float*)d_in[8];
    const float* h0b = (const float*)d_in[9];
    const float* c0b = (const float*)d_in[10];
    float* out = (float*)d_out;

    char* ws = (char*)d_ws;
    size_t off = 0;
    unsigned short* WcatP = (unsigned short*)(ws + off); off += (size_t)G4 * KW * 2;   // 2 MB
    unsigned short* WihP  = (unsigned short*)(ws + off); off += (size_t)G4 * KX * 2;   // 1.3 MB
    float* biasP          = (float*)(ws + off);          off += (size_t)G4 * 4;
    unsigned short* hhi0  = (unsigned short*)(ws + off); off += (size_t)BT * HH * 2;
    unsigned short* hhi1  = (unsigned short*)(ws + off); off += (size_t)BT * HH * 2;
    unsigned short* hlo0  = (unsigned short*)(ws + off); off += (size_t)BT * HH * 2;
    unsigned short* hlo1  = (unsigned short*)(ws + off); off += (size_t)BT * HH * 2;
    float* cbuf           = (float*)(ws + off);          off += (size_t)BT * HH * 4;   // 1 MB
    unsigned short* Xbf   = (unsigned short*)(ws + off); off += (size_t)TT * BT * KX * 2; // 21 MB
    unsigned short* xprojP= (unsigned short*)(ws + off); off += (size_t)TT * BT * G4 * 2; // 134 MB

    prep_w<<<G4, 256, 0, stream>>>(Wih, Whh, bih, bhh, WcatP, WihP, biasP);
    prep_h<<<BT, 256, 0, stream>>>(h0a, c0a, h0b, c0b, hhi0, hlo0, cbuf);
    gather_x<<<(TT * BT * 40) / 256, 256, 0, stream>>>(s1, s2, emb, Xbf);
    gemm_x<<<4096, 512, 0, stream>>>(Xbf, WihP, xprojP);

    unsigned short* hhi[2] = { hhi0, hhi1 };
    unsigned short* hlo[2] = { hlo0, hlo1 };
    for (int t = 0; t < TT; ++t) {
        int pi = t & 1, po = pi ^ 1;
        lstm_step<<<256, 256, 0, stream>>>(WcatP, biasP, xprojP,
                                           hhi[pi], hlo[pi], cbuf,
                                           hhi[po], hlo[po], t);
    }
    // t=63 (odd) writes buffer 0
    finalize<<<BB, 64, 0, stream>>>(hhi0, hlo0, out);
}